// Round 1
// baseline (2249.746 us; speedup 1.0000x reference)
//
#include <hip/hip_runtime.h>

typedef unsigned long long u64;
typedef unsigned int u32;

#define HF 32
#define TBL_BITS 22
#define TBL_SIZE (1u << TBL_BITS)
#define CC_ITERS 32
#define EMPTY_KEY 0xFFFFFFFFFFFFFFFFull

// ---------------- GCN 1 ----------------

__global__ void k_deg1(const int2* __restrict__ edges, float* __restrict__ deg1, int E) {
    int e = blockIdx.x * blockDim.x + threadIdx.x;
    if (e >= E) return;
    atomicAdd(&deg1[edges[e].y], 1.0f);
}

// h = x @ W1 ; dis1 = 1/sqrt(deg+1) ; hs = h * dis1
__global__ void k_h1(const float* __restrict__ x, const float* __restrict__ W1,
                     const float* __restrict__ deg1, float* __restrict__ hs,
                     float* __restrict__ dis1, int N) {
    __shared__ float w[96];
    int tid = threadIdx.x;
    if (tid < 96) w[tid] = W1[tid];
    __syncthreads();
    int t = blockIdx.x * blockDim.x + tid;
    int i = t >> 3, fg = t & 7;
    if (i >= N) return;
    float x0 = x[3 * i + 0], x1 = x[3 * i + 1], x2 = x[3 * i + 2];
    float dis = 1.0f / sqrtf(deg1[i] + 1.0f);
    int f = fg * 4;
    float4 h;
    h.x = (x0 * w[f + 0] + x1 * w[32 + f + 0] + x2 * w[64 + f + 0]) * dis;
    h.y = (x0 * w[f + 1] + x1 * w[32 + f + 1] + x2 * w[64 + f + 1]) * dis;
    h.z = (x0 * w[f + 2] + x1 * w[32 + f + 2] + x2 * w[64 + f + 2]) * dis;
    h.w = (x0 * w[f + 3] + x1 * w[32 + f + 3] + x2 * w[64 + f + 3]) * dis;
    ((float4*)hs)[i * 8 + fg] = h;
    if (fg == 0) dis1[i] = dis;
}

// acc[d] += hs[s] over edges
__global__ void k_scatter1(const int2* __restrict__ edges, const float* __restrict__ hs,
                           float* __restrict__ acc, int E) {
    int t = blockIdx.x * blockDim.x + threadIdx.x;
    int e = t >> 3, fg = t & 7;
    if (e >= E) return;
    int2 ed = edges[e];
    float4 v = ((const float4*)hs)[ed.x * 8 + fg];
    float* d = &acc[ed.y * HF + fg * 4];
    atomicAdd(d + 0, v.x);
    atomicAdd(d + 1, v.y);
    atomicAdd(d + 2, v.z);
    atomicAdd(d + 3, v.w);
}

// x1 = relu(dis*(acc+hs)+b1)  (in place over hs); per-node dots with w_pool; lab init
__global__ void k_x1dots(const float* __restrict__ acc, float* __restrict__ hsx1,
                         const float* __restrict__ dis1, const float* __restrict__ b1,
                         const float* __restrict__ wp, float* __restrict__ a_src,
                         float* __restrict__ a_dst, int* __restrict__ lab, int N) {
    __shared__ float wpl[64];
    __shared__ float b1l[32];
    int tid = threadIdx.x;
    if (tid < 64) wpl[tid] = wp[tid];
    if (tid < 32) b1l[tid] = b1[tid];
    __syncthreads();
    int t = blockIdx.x * blockDim.x + tid;
    int i = t >> 3, fg = t & 7;
    if (i >= N) return;
    float4 a = ((const float4*)acc)[i * 8 + fg];
    float4 h = ((const float4*)hsx1)[i * 8 + fg];
    float dis = dis1[i];
    int f = fg * 4;
    float4 r;
    r.x = fmaxf(dis * (a.x + h.x) + b1l[f + 0], 0.0f);
    r.y = fmaxf(dis * (a.y + h.y) + b1l[f + 1], 0.0f);
    r.z = fmaxf(dis * (a.z + h.z) + b1l[f + 2], 0.0f);
    r.w = fmaxf(dis * (a.w + h.w) + b1l[f + 3], 0.0f);
    ((float4*)hsx1)[i * 8 + fg] = r;
    float ps = r.x * wpl[f + 0] + r.y * wpl[f + 1] + r.z * wpl[f + 2] + r.w * wpl[f + 3];
    float pd = r.x * wpl[32 + f + 0] + r.y * wpl[32 + f + 1] + r.z * wpl[32 + f + 2] + r.w * wpl[32 + f + 3];
#pragma unroll
    for (int o = 4; o; o >>= 1) {
        ps += __shfl_xor(ps, o);
        pd += __shfl_xor(pd, o);
    }
    if (fg == 0) {
        a_src[i] = ps;
        a_dst[i] = pd;
        lab[i] = i;
    }
}

// ---------------- edge selection + CC ----------------

__global__ void k_select(const int2* __restrict__ edges, const float* __restrict__ a_src,
                         const float* __restrict__ a_dst, const float* __restrict__ bp,
                         long long* __restrict__ seluv, int* __restrict__ selcnt, int E) {
    int e = blockIdx.x * blockDim.x + threadIdx.x;
    if (e >= E) return;
    int2 ed = edges[e];
    float z = a_src[ed.x] + a_dst[ed.y] + bp[0];
    float score = 1.0f / (1.0f + expf(-z));
    if (score > 0.5f) {
        int pos = atomicAdd(selcnt, 1);
        seluv[pos] = ((long long)ed.x << 32) | (u32)ed.y;
    }
}

__global__ void k_cc_edge(const long long* __restrict__ seluv, const int* __restrict__ pcnt,
                          int* __restrict__ lab, int* __restrict__ changed, int t) {
    if (t > 0 && changed[t - 1] == 0) return;
    int n = *pcnt;
    int ch = 0;
    for (int idx = blockIdx.x * blockDim.x + threadIdx.x; idx < n; idx += gridDim.x * blockDim.x) {
        long long p = seluv[idx];
        int u = (int)(p >> 32), v = (int)(u32)p;
        int lu = lab[u], lv = lab[v];
        int m = min(lu, lv);
        if (lu > m) {
            int old = atomicMin(&lab[u], m);
            if (old > m) ch = 1;
        }
        if (lv > m) {
            int old = atomicMin(&lab[v], m);
            if (old > m) ch = 1;
        }
    }
    if (ch) changed[t] = 1;
}

__global__ void k_cc_jump(int* __restrict__ lab, int* __restrict__ changed, int t, int N) {
    if (t > 0 && changed[t - 1] == 0) return;
    int i = blockIdx.x * blockDim.x + threadIdx.x;
    if (i >= N) return;
    int l = lab[i];
    int m = min(l, lab[l]);
    m = min(m, lab[m]);
    if (m < l) {
        lab[i] = m;
        changed[t] = 1;
    }
}

// ---------------- component stats ----------------

// cnt[g] += 1, ssum[g] += score over selected edges, g = lab[src]; wave-aggregated
__global__ void k_cnt_ssum(const long long* __restrict__ seluv, const int* __restrict__ pcnt,
                           const float* __restrict__ a_src, const float* __restrict__ a_dst,
                           const float* __restrict__ bp, const int* __restrict__ lab,
                           float* __restrict__ cnt, float* __restrict__ ssum) {
    int n = *pcnt;
    float bpv = bp[0];
    for (int base = blockIdx.x * blockDim.x; base < n; base += gridDim.x * blockDim.x) {
        int idx = base + threadIdx.x;
        bool valid = idx < n;
        int g = -1;
        float score = 0.0f;
        if (valid) {
            long long p = seluv[idx];
            int s = (int)(p >> 32), d = (int)(u32)p;
            float z = a_src[s] + a_dst[d] + bpv;
            score = 1.0f / (1.0f + expf(-z));
            g = lab[s];
        }
        u64 m = __ballot(valid);
        while (m) {
            int leader = __ffsll(m) - 1;
            int g0 = __shfl(g, leader);
            bool match = valid && (g == g0);
            float c = match ? 1.0f : 0.0f;
            float sv = match ? score : 0.0f;
#pragma unroll
            for (int o = 32; o; o >>= 1) {
                c += __shfl_xor(c, o);
                sv += __shfl_xor(sv, o);
            }
            if ((int)(threadIdx.x & 63) == leader) {
                atomicAdd(&cnt[g0], c);
                atomicAdd(&ssum[g0], sv);
            }
            m &= ~__ballot(match);
        }
    }
}

// giant-label detection: argmax over cnt
__global__ void k_findgl(const float* __restrict__ cnt, u64* __restrict__ glpack, int N) {
    int i = blockIdx.x * blockDim.x + threadIdx.x;
    u64 v = 0;
    if (i < N) v = ((u64)__float_as_uint(cnt[i]) << 32) | (u32)i;
#pragma unroll
    for (int o = 32; o; o >>= 1) {
        u64 ov = __shfl_xor(v, o);
        v = v > ov ? v : ov;
    }
    if ((int)(threadIdx.x & 63) == 0) atomicMax(glpack, v);
}

// nx[lab[i]] += x1[i], giant row via LDS per block
__global__ void k_nx_scatter(const float* __restrict__ x1, const int* __restrict__ lab,
                             const u64* __restrict__ glpack, float* __restrict__ nx, int N) {
    __shared__ float ls[HF];
    int tid = threadIdx.x;
    if (tid < HF) ls[tid] = 0.0f;
    __syncthreads();
    int gl = (int)(u32)(*glpack);
    int t = blockIdx.x * blockDim.x + tid;
    int i = t >> 3, fg = t & 7;
    if (i < N) {
        int l = lab[i];
        float4 v = ((const float4*)x1)[i * 8 + fg];
        if (l == gl) {
            atomicAdd(&ls[fg * 4 + 0], v.x);
            atomicAdd(&ls[fg * 4 + 1], v.y);
            atomicAdd(&ls[fg * 4 + 2], v.z);
            atomicAdd(&ls[fg * 4 + 3], v.w);
        } else {
            float* d = &nx[l * HF + fg * 4];
            atomicAdd(d + 0, v.x);
            atomicAdd(d + 1, v.y);
            atomicAdd(d + 2, v.z);
            atomicAdd(d + 3, v.w);
        }
    }
    __syncthreads();
    if (tid < HF) {
        float s = ls[tid];
        if (s != 0.0f) atomicAdd(&nx[gl * HF + tid], s);
    }
}

// ---------------- coarse graph ----------------

__global__ void k_hash_insert(const int2* __restrict__ edges, const int* __restrict__ lab,
                              u64* __restrict__ htab, float* __restrict__ deg3,
                              const u64* __restrict__ glpack, int E) {
    __shared__ float dcnt;
    if (threadIdx.x == 0) dcnt = 0.0f;
    __syncthreads();
    int e = blockIdx.x * blockDim.x + threadIdx.x;
    int gl = (int)(u32)(*glpack);
    bool won = false;
    int rv = -1;
    if (e < E) {
        int2 ed = edges[e];
        int ru = lab[ed.x];
        rv = lab[ed.y];
        if (ru != rv) {
            u64 key = ((u64)(u32)ru << 32) | (u32)rv;
            u32 slot = (u32)((key * 0x9E3779B97F4A7C15ull) >> (64 - TBL_BITS));
            for (;;) {
                u64 cur = htab[slot];
                if (cur == key) break;
                if (cur == EMPTY_KEY) {
                    u64 prev = atomicCAS(&htab[slot], EMPTY_KEY, key);
                    if (prev == EMPTY_KEY) { won = true; break; }
                    if (prev == key) break;
                }
                slot = (slot + 1) & (TBL_SIZE - 1);
            }
        }
    }
    if (won) {
        if (rv == gl) atomicAdd(&dcnt, 1.0f);
        else atomicAdd(&deg3[rv], 1.0f);
    }
    __syncthreads();
    if (threadIdx.x == 0 && dcnt != 0.0f) atomicAdd(&deg3[gl], dcnt);
}

// per rep node: cscore, dis3, hs3 = (nx*cscore @ W3) * dis3
__global__ void k_h3(const float* __restrict__ nx, const float* __restrict__ cnt,
                     const float* __restrict__ ssum, const float* __restrict__ deg3,
                     const int* __restrict__ lab, const float* __restrict__ W3,
                     float* __restrict__ hs3, float* __restrict__ dis3, int N) {
    __shared__ float w[HF * HF];
    int tid = threadIdx.x;
    for (int k = tid; k < HF * HF; k += blockDim.x) w[k] = W3[k];
    __syncthreads();
    int i = blockIdx.x * blockDim.x + tid;
    if (i >= N) return;
    if (lab[i] != i) {
        dis3[i] = 0.0f;
        return;
    }
    float cn = cnt[i];
    float c = cn > 0.0f ? ssum[i] / fmaxf(cn, 1.0f) : 1.0f;
    float d3 = 1.0f / sqrtf(deg3[i] + 1.0f);
    dis3[i] = d3;
    float scale = c * d3;
    float r[HF];
#pragma unroll
    for (int f = 0; f < HF; f++) r[f] = 0.0f;
    for (int k = 0; k < HF; k++) {
        float xv = nx[i * HF + k];
#pragma unroll
        for (int f = 0; f < HF; f++) r[f] += xv * w[k * HF + f];
    }
#pragma unroll
    for (int f = 0; f < HF; f++) hs3[i * HF + f] = r[f] * scale;
}

// acc3[b] += hs3[a] for each unique coarse edge (a,b); giant row via LDS
__global__ void k_hash_scatter(const u64* __restrict__ htab, const float* __restrict__ hs3,
                               float* __restrict__ acc3, const u64* __restrict__ glpack) {
    __shared__ float ls[HF];
    int tid = threadIdx.x;
    if (tid < HF) ls[tid] = 0.0f;
    __syncthreads();
    int gl = (int)(u32)(*glpack);
    int t = blockIdx.x * blockDim.x + tid;
    u32 slot = (u32)(t >> 3);
    int fg = t & 7;
    u64 key = htab[slot];
    if (key != EMPTY_KEY) {
        int a = (int)(key >> 32), b = (int)(u32)key;
        float4 v = ((const float4*)hs3)[a * 8 + fg];
        if (b == gl) {
            atomicAdd(&ls[fg * 4 + 0], v.x);
            atomicAdd(&ls[fg * 4 + 1], v.y);
            atomicAdd(&ls[fg * 4 + 2], v.z);
            atomicAdd(&ls[fg * 4 + 3], v.w);
        } else {
            float* d = &acc3[b * HF + fg * 4];
            atomicAdd(d + 0, v.x);
            atomicAdd(d + 1, v.y);
            atomicAdd(d + 2, v.z);
            atomicAdd(d + 3, v.w);
        }
    }
    __syncthreads();
    if (tid < HF) {
        float s = ls[tid];
        if (s != 0.0f) atomicAdd(&acc3[gl * HF + tid], s);
    }
}

// x3 = relu(dis3*(acc3+hs3)+b3) at reps; pool into gs/gc by batch
__global__ void k_final(const float* __restrict__ acc3, const float* __restrict__ hs3,
                        const float* __restrict__ dis3, const int* __restrict__ lab,
                        const int* __restrict__ batch, const float* __restrict__ b3,
                        float* __restrict__ gs, float* __restrict__ gc, int N) {
    int t = blockIdx.x * blockDim.x + threadIdx.x;
    int i = t >> 3, fg = t & 7;
    if (i >= N) return;
    if (lab[i] != i) return;
    float d3 = dis3[i];
    float4 a = ((const float4*)acc3)[i * 8 + fg];
    float4 h = ((const float4*)hs3)[i * 8 + fg];
    int f = fg * 4;
    float4 x3;
    x3.x = fmaxf(d3 * (a.x + h.x) + b3[f + 0], 0.0f);
    x3.y = fmaxf(d3 * (a.y + h.y) + b3[f + 1], 0.0f);
    x3.z = fmaxf(d3 * (a.z + h.z) + b3[f + 2], 0.0f);
    x3.w = fmaxf(d3 * (a.w + h.w) + b3[f + 3], 0.0f);
    int b = batch[i];
    float* g = &gs[b * HF + f];
    atomicAdd(g + 0, x3.x);
    atomicAdd(g + 1, x3.y);
    atomicAdd(g + 2, x3.z);
    atomicAdd(g + 3, x3.w);
    if (fg == 0) atomicAdd(&gc[b], 1.0f);
}

__global__ void k_out(const float* __restrict__ gs, const float* __restrict__ gc,
                      const float* __restrict__ Wf, const float* __restrict__ bf,
                      float* __restrict__ out, int B) {
    int b = threadIdx.x + blockIdx.x * blockDim.x;
    if (b >= B) return;
    float inv = 1.0f / fmaxf(gc[b], 1.0f);
    float z = 0.0f;
#pragma unroll
    for (int f = 0; f < HF; f++) z += gs[b * HF + f] * inv * Wf[f];
    z += bf[0];
    out[b] = 1.0f / (1.0f + expf(-z));
}

// ---------------- host ----------------

static inline size_t align256(size_t x) { return (x + 255) & ~(size_t)255; }

extern "C" void kernel_launch(void* const* d_in, const int* in_sizes, int n_in,
                              void* d_out, int out_size, void* d_ws, size_t ws_size,
                              hipStream_t stream) {
    const float* x = (const float*)d_in[0];
    const int2* edges = (const int2*)d_in[1];
    const int* batch = (const int*)d_in[2];
    const float* W1 = (const float*)d_in[3];
    const float* b1 = (const float*)d_in[4];
    const float* wp = (const float*)d_in[5];
    const float* bp = (const float*)d_in[6];
    const float* W3 = (const float*)d_in[7];
    const float* b3 = (const float*)d_in[8];
    const float* Wf = (const float*)d_in[9];
    const float* bf = (const float*)d_in[10];
    float* outp = (float*)d_out;

    const int N = in_sizes[2];
    const int E = in_sizes[1] / 2;
    const int B = out_size;

    char* p = (char*)d_ws;
    size_t off = 0;
    auto alloc = [&](size_t bytes) -> void* {
        void* r = p + off;
        off = align256(off + bytes);
        return r;
    };
    float* f0 = (float*)alloc((size_t)N * HF * 4);   // hs -> x1 -> hs3
    float* f1 = (float*)alloc((size_t)N * HF * 4);   // acc -> nx -> acc3
    float* deg1 = (float*)alloc((size_t)N * 4);
    float* dis1 = (float*)alloc((size_t)N * 4);
    float* a_src = (float*)alloc((size_t)N * 4);
    float* a_dst = (float*)alloc((size_t)N * 4);
    int* lab = (int*)alloc((size_t)N * 4);
    float* cnt = (float*)alloc((size_t)N * 4);
    float* ssum = (float*)alloc((size_t)N * 4);
    float* deg3 = (float*)alloc((size_t)N * 4);
    float* dis3 = (float*)alloc((size_t)N * 4);
    long long* seluv = (long long*)alloc((size_t)E * 8);
    int* selcnt = (int*)alloc(4);
    int* changed = (int*)alloc(CC_ITERS * 4);
    u64* glpack = (u64*)alloc(8);
    float* gs = (float*)alloc((size_t)B * HF * 4);
    float* gc = (float*)alloc((size_t)B * 4);
    u64* htab = (u64*)alloc((size_t)TBL_SIZE * 8);
    (void)ws_size; (void)n_in;

    const int nb_e = (E + 255) / 256;
    const int nb_e8 = (int)(((size_t)E * 8 + 255) / 256);
    const int nb_n8 = (int)(((size_t)N * 8 + 255) / 256);
    const int nb_n = (N + 255) / 256;
    const int nb_tbl8 = (int)(((size_t)TBL_SIZE * 8) / 256);

    hipMemsetAsync(deg1, 0, (size_t)N * 4, stream);
    hipMemsetAsync(f1, 0, (size_t)N * HF * 4, stream);
    hipMemsetAsync(cnt, 0, (size_t)N * 4, stream);
    hipMemsetAsync(ssum, 0, (size_t)N * 4, stream);
    hipMemsetAsync(deg3, 0, (size_t)N * 4, stream);
    hipMemsetAsync(selcnt, 0, 4, stream);
    hipMemsetAsync(changed, 0, CC_ITERS * 4, stream);
    hipMemsetAsync(glpack, 0, 8, stream);
    hipMemsetAsync(gs, 0, (size_t)B * HF * 4, stream);
    hipMemsetAsync(gc, 0, (size_t)B * 4, stream);
    hipMemsetAsync(htab, 0xFF, (size_t)TBL_SIZE * 8, stream);

    k_deg1<<<nb_e, 256, 0, stream>>>(edges, deg1, E);
    k_h1<<<nb_n8, 256, 0, stream>>>(x, W1, deg1, f0, dis1, N);
    k_scatter1<<<nb_e8, 256, 0, stream>>>(edges, f0, f1, E);
    k_x1dots<<<nb_n8, 256, 0, stream>>>(f1, f0, dis1, b1, wp, a_src, a_dst, lab, N);
    k_select<<<nb_e, 256, 0, stream>>>(edges, a_src, a_dst, bp, seluv, selcnt, E);
    for (int t = 0; t < CC_ITERS; t++) {
        k_cc_edge<<<2048, 256, 0, stream>>>(seluv, selcnt, lab, changed, t);
        k_cc_jump<<<nb_n, 256, 0, stream>>>(lab, changed, t, N);
    }
    k_cnt_ssum<<<1024, 256, 0, stream>>>(seluv, selcnt, a_src, a_dst, bp, lab, cnt, ssum);
    k_findgl<<<nb_n, 256, 0, stream>>>(cnt, glpack, N);
    hipMemsetAsync(f1, 0, (size_t)N * HF * 4, stream);
    k_nx_scatter<<<nb_n8, 256, 0, stream>>>(f0, lab, glpack, f1, N);
    k_hash_insert<<<nb_e, 256, 0, stream>>>(edges, lab, htab, deg3, glpack, E);
    k_h3<<<nb_n, 256, 0, stream>>>(f1, cnt, ssum, deg3, lab, W3, f0, dis3, N);
    hipMemsetAsync(f1, 0, (size_t)N * HF * 4, stream);
    k_hash_scatter<<<nb_tbl8, 256, 0, stream>>>(htab, f0, f1, glpack);
    k_final<<<nb_n8, 256, 0, stream>>>(f1, f0, dis3, lab, batch, b3, gs, gc, N);
    k_out<<<1, 128, 0, stream>>>(gs, gc, Wf, bf, outp, B);
}